// Round 2
// baseline (555.155 us; speedup 1.0000x reference)
//
#include <hip/hip_runtime.h>
#include <hip/hip_bf16.h>
#include <stdint.h>
#include <stddef.h>

// LinearMoE: B=4096 tokens, D=2048, H=2048, E=8, K=2.  fp32 in/out.
#define B_TOK 4096
#define D_DIM 2048
#define H_DIM 2048
#define E_NUM 8

typedef __bf16 bf16;
typedef __attribute__((ext_vector_type(8))) __bf16 bf16x8;
typedef __attribute__((ext_vector_type(4))) float f32x4;

// ---------------- ws layout ----------------
// [0,32)            counts[8] int
// [4096,135168)     entries[8][4096] int   value=(token<<1)|slot
// [135168,167936)   tk_idx[4096][2] int
// [167936,200704)   tk_w[4096][2] float
// fast path only:
// [262144, +16.78M) xbf [4096][2048] bf16
// [17039360, +67.1M) WeT [8][2048][2048] bf16 (h-major, d-contiguous)
#define WS_COUNTS   0
#define WS_ENTRIES  4096
#define WS_TKIDX    135168
#define WS_TKW      167936
#define WS_XBF      262144
#define WS_WET      17039360
#define WS_BIG_NEED 84148224ULL

__device__ __forceinline__ void gload16(const void* g, void* l) {
  __builtin_amdgcn_global_load_lds(
      (const __attribute__((address_space(1))) void*)g,
      (__attribute__((address_space(3))) void*)l, 16, 0, 0);
}

__global__ void zero_counts(int* counts) {
  if (threadIdx.x < E_NUM) counts[threadIdx.x] = 0;
}

// One wave per token. fp64 accumulation so top-2 ordering matches np ref.
__global__ void gating_kernel(const float* __restrict__ x,
                              const float* __restrict__ Wg,
                              const float* __restrict__ bg,
                              int* counts, int* entries,
                              int* tk_idx, float* tk_w) {
  int gtid = blockIdx.x * blockDim.x + threadIdx.x;
  int b = gtid >> 6;
  int lane = threadIdx.x & 63;
  if (b >= B_TOK) return;
  const float* xrow = x + (size_t)b * D_DIM;

  double acc[E_NUM];
#pragma unroll
  for (int e = 0; e < E_NUM; e++) acc[e] = 0.0;

#pragma unroll
  for (int i = 0; i < 8; i++) {
    int d0 = i * 256 + lane * 4;
    f32x4 xv = *(const f32x4*)(xrow + d0);
#pragma unroll
    for (int j = 0; j < 4; j++) {
      double xf = (double)xv[j];
      f32x4 w0 = *(const f32x4*)(Wg + (size_t)(d0 + j) * E_NUM);
      f32x4 w1 = *(const f32x4*)(Wg + (size_t)(d0 + j) * E_NUM + 4);
#pragma unroll
      for (int e = 0; e < 4; e++) acc[e] += xf * (double)w0[e];
#pragma unroll
      for (int e = 0; e < 4; e++) acc[4 + e] += xf * (double)w1[e];
    }
  }
#pragma unroll
  for (int e = 0; e < E_NUM; e++) {
    double v = acc[e];
#pragma unroll
    for (int off = 32; off >= 1; off >>= 1) v += __shfl_xor(v, off, 64);
    acc[e] = v;
  }

  if (lane == 0) {
    double lg[E_NUM];
#pragma unroll
    for (int e = 0; e < E_NUM; e++) lg[e] = acc[e] + (double)bg[e];
    int i0 = 0; double v0 = lg[0];
#pragma unroll
    for (int e = 1; e < E_NUM; e++) if (lg[e] > v0) { v0 = lg[e]; i0 = e; }
    int i1 = -1; double v1 = -1e300;
#pragma unroll
    for (int e = 0; e < E_NUM; e++)
      if (e != i0 && lg[e] > v1) { v1 = lg[e]; i1 = e; }
    double m = v0;  // v0 is the max
    double den = 0.0;
    double p0 = 0.0, p1 = 0.0;
#pragma unroll
    for (int e = 0; e < E_NUM; e++) {
      double pe = exp(lg[e] - m);
      den += pe;
      if (e == i0) p0 = pe;
      if (e == i1) p1 = pe;
    }
    tk_idx[2 * b] = i0;
    tk_idx[2 * b + 1] = i1;
    tk_w[2 * b] = (float)(p0 / den);
    tk_w[2 * b + 1] = (float)(p1 / den);
    int q0 = atomicAdd(&counts[i0], 1);
    entries[i0 * B_TOK + q0] = (b << 1);
    int q1 = atomicAdd(&counts[i1], 1);
    entries[i1 * B_TOK + q1] = (b << 1) | 1;
  }
}

// out[b][h] = w0*be[e0][h] + w1*be[e1][h]  (overwrites poison; GEMM atomics add on top)
__global__ void prefill_kernel(const float* __restrict__ be,
                               const int* __restrict__ tk_idx,
                               const float* __restrict__ tk_w,
                               float* __restrict__ out) {
  int idx = blockIdx.x * blockDim.x + threadIdx.x;  // B*H/4 threads
  int b = idx >> 9;
  int hc = (idx & 511) * 4;
  int e0 = tk_idx[2 * b], e1 = tk_idx[2 * b + 1];
  float w0 = tk_w[2 * b], w1 = tk_w[2 * b + 1];
  f32x4 b0 = *(const f32x4*)(be + (size_t)e0 * H_DIM + hc);
  f32x4 b1 = *(const f32x4*)(be + (size_t)e1 * H_DIM + hc);
  f32x4 o;
#pragma unroll
  for (int j = 0; j < 4; j++) o[j] = w0 * b0[j] + w1 * b1[j];
  *(f32x4*)(out + (size_t)b * H_DIM + hc) = o;
}

// ---- fast path helpers ----
__global__ void xcvt_kernel(const float* __restrict__ x, bf16* __restrict__ xbf) {
  int idx = blockIdx.x * blockDim.x + threadIdx.x;  // B*D/8 threads
  f32x4 a = *(const f32x4*)(x + (size_t)idx * 8);
  f32x4 c = *(const f32x4*)(x + (size_t)idx * 8 + 4);
  bf16x8 o;
#pragma unroll
  for (int j = 0; j < 4; j++) { o[j] = (bf16)a[j]; o[4 + j] = (bf16)c[j]; }
  *(bf16x8*)(xbf + (size_t)idx * 8) = o;
}

// We[e][d][h] fp32 -> WeT[e][h][d] bf16, 64x64 tiles
__global__ void transpose_cvt_we(const float* __restrict__ We, bf16* __restrict__ WeT) {
  __shared__ __align__(16) float tile[64][68];  // 68*4=272 (16-mult): f32x4-aligned rows
  int e = blockIdx.z;
  int h0 = blockIdx.x * 64, d0 = blockIdx.y * 64;
  int t = threadIdx.x;
  int dr = t >> 2, hc = (t & 3) * 16;
  const float* src = We + ((size_t)e * D_DIM + d0 + dr) * H_DIM + h0 + hc;
#pragma unroll
  for (int i = 0; i < 4; i++)
    *(f32x4*)(&tile[dr][hc + 4 * i]) = *(const f32x4*)(src + 4 * i);
  __syncthreads();
  int h = t >> 2, dc = (t & 3) * 16;
  bf16x8 o0, o1;
#pragma unroll
  for (int j = 0; j < 8; j++) {
    o0[j] = (bf16)tile[dc + j][h];
    o1[j] = (bf16)tile[dc + 8 + j][h];
  }
  bf16* dst = WeT + (size_t)e * H_DIM * D_DIM + (size_t)(h0 + h) * D_DIM + d0 + dc;
  *(bf16x8*)dst = o0;
  *(bf16x8*)(dst + 8) = o1;
}

// ---- GEMM epilogue (shared) is inlined in both kernels ----
// LDS fragment layout: chunk c = ci*64 + q*16 + r holds A[m=16ci+r][k=8q..8q+7]
// -> fragment read for (ci): lane l reads byte ci*1024 + l*16 (contiguous, conflict-free)

__global__ __launch_bounds__(256) void moe_gemm_fast(
    const bf16* __restrict__ xbf, const bf16* __restrict__ WeT,
    const int* __restrict__ counts, const int* __restrict__ entries,
    const float* __restrict__ tk_w, float* __restrict__ out) {
  __shared__ __align__(16) bf16 As_f[4096];
  __shared__ __align__(16) bf16 Bs_f[4096];
  int e = blockIdx.y >> 5, mtile = blockIdx.y & 31;
  int cnt = counts[e];
  if (mtile * 128 >= cnt) return;
  int n0 = blockIdx.x * 128;
  int tid = threadIdx.x, lane = tid & 63, w = tid >> 6;
  int r = lane & 15, q = lane >> 4;
  const int* ereg = entries + e * B_TOK;
  const bf16* wet_e = WeT + (size_t)e * H_DIM * D_DIM;

  const bf16* srcA[2]; const bf16* srcB[2];
  bf16 *dstA[2], *dstB[2];
#pragma unroll
  for (int j = 0; j < 2; j++) {
    int ci = w * 2 + j;
    int m = mtile * 128 + 16 * ci + r;
    int tok = ereg[min(m, cnt - 1)] >> 1;
    srcA[j] = xbf + (size_t)tok * D_DIM + 8 * q;
    dstA[j] = As_f + ci * 512;            // wave-uniform base; HW adds lane*16B
    srcB[j] = wet_e + (size_t)(n0 + 16 * ci + r) * D_DIM + 8 * q;
    dstB[j] = Bs_f + ci * 512;
  }
  int wm4 = (w & 1) * 4, wn4 = (w >> 1) * 4;

  f32x4 acc[4][4];
#pragma unroll
  for (int i = 0; i < 4; i++)
#pragma unroll
    for (int j = 0; j < 4; j++) acc[i][j] = (f32x4){0.f, 0.f, 0.f, 0.f};

  for (int k0 = 0; k0 < D_DIM; k0 += 32) {
    __syncthreads();
    gload16(srcA[0] + k0, dstA[0]);
    gload16(srcA[1] + k0, dstA[1]);
    gload16(srcB[0] + k0, dstB[0]);
    gload16(srcB[1] + k0, dstB[1]);
    __syncthreads();
    bf16x8 af[4], bfr[4];
#pragma unroll
    for (int i = 0; i < 4; i++)
      af[i] = *(const bf16x8*)(As_f + (wm4 + i) * 512 + lane * 8);
#pragma unroll
    for (int j = 0; j < 4; j++)
      bfr[j] = *(const bf16x8*)(Bs_f + (wn4 + j) * 512 + lane * 8);
#pragma unroll
    for (int i = 0; i < 4; i++)
#pragma unroll
      for (int j = 0; j < 4; j++)
        acc[i][j] = __builtin_amdgcn_mfma_f32_16x16x32_bf16(af[i], bfr[j],
                                                            acc[i][j], 0, 0, 0);
  }

  int base_r = mtile * 128, wm = (w & 1) * 64, wn = (w >> 1) * 64;
#pragma unroll
  for (int i = 0; i < 4; i++)
#pragma unroll
    for (int reg = 0; reg < 4; reg++) {
      int rg = base_r + wm + 16 * i + q * 4 + reg;
      if (rg < cnt) {
        int ent = ereg[rg];
        int tok = ent >> 1, slot = ent & 1;
        float wgt = tk_w[2 * tok + slot];
        float* orow = out + (size_t)tok * H_DIM + n0 + wn;
#pragma unroll
        for (int j = 0; j < 4; j++)
          atomicAdd(orow + 16 * j + r, wgt * acc[i][j][reg]);
      }
    }
}

// Small-ws path: A gathered per-thread fp32->bf16; B staged raw fp32 via
// global_load_lds then transposed+converted to fragment layout each K-iter.
__global__ __launch_bounds__(256) void moe_gemm_slow(
    const float* __restrict__ x, const float* __restrict__ We,
    const int* __restrict__ counts, const int* __restrict__ entries,
    const float* __restrict__ tk_w, float* __restrict__ out) {
  __shared__ __align__(16) bf16 As_f[4096];
  __shared__ __align__(16) bf16 Bs_f[4096];
  __shared__ __align__(16) float Braw[4096];  // [k<32][n<128]
  int e = blockIdx.y >> 5, mtile = blockIdx.y & 31;
  int cnt = counts[e];
  if (mtile * 128 >= cnt) return;
  int n0 = blockIdx.x * 128;
  int tid = threadIdx.x, lane = tid & 63, w = tid >> 6;
  int r = lane & 15, q = lane >> 4;
  const int* ereg = entries + e * B_TOK;

  // A: 2 chunks/thread (c = tid, tid+256)
  const float* srcA[2]; bf16* dstA[2];
#pragma unroll
  for (int s = 0; s < 2; s++) {
    int c = tid + s * 256;
    int ci = c >> 6, qq = (c >> 4) & 3, rr = c & 15;
    int m = mtile * 128 + 16 * ci + rr;
    int tok = ereg[min(m, cnt - 1)] >> 1;
    srcA[s] = x + (size_t)tok * D_DIM + 8 * qq;
    dstA[s] = As_f + c * 8;
  }
  // B raw staging: 4 gloads/thread
  const float* srcBr[4]; float* dstBr[4];
#pragma unroll
  for (int i = 0; i < 4; i++) {
    int row = (w * 4 + i) * 2 + (lane >> 5);
    srcBr[i] = We + ((size_t)e * D_DIM + row) * H_DIM + n0 + (lane & 31) * 4;
    dstBr[i] = Braw + (w * 4 + i) * 256;  // wave-uniform base
  }
  // B transpose stage: 2 chunks/thread
  int n2[2], q2[2]; bf16* dstB2[2];
#pragma unroll
  for (int s = 0; s < 2; s++) {
    int c = tid + s * 256;
    n2[s] = 16 * (c >> 6) + (c & 15);
    q2[s] = (c >> 4) & 3;
    dstB2[s] = Bs_f + c * 8;
  }
  int wm4 = (w & 1) * 4, wn4 = (w >> 1) * 4;

  f32x4 acc[4][4];
#pragma unroll
  for (int i = 0; i < 4; i++)
#pragma unroll
    for (int j = 0; j < 4; j++) acc[i][j] = (f32x4){0.f, 0.f, 0.f, 0.f};

  for (int k0 = 0; k0 < D_DIM; k0 += 32) {
    __syncthreads();
#pragma unroll
    for (int i = 0; i < 4; i++)
      gload16(srcBr[i] + (size_t)k0 * H_DIM, dstBr[i]);
#pragma unroll
    for (int s = 0; s < 2; s++) {
      f32x4 a0 = *(const f32x4*)(srcA[s] + k0);
      f32x4 a1 = *(const f32x4*)(srcA[s] + k0 + 4);
      bf16x8 av;
#pragma unroll
      for (int j = 0; j < 4; j++) { av[j] = (bf16)a0[j]; av[4 + j] = (bf16)a1[j]; }
      *(bf16x8*)dstA[s] = av;
    }
    __syncthreads();  // Braw + As_f visible
#pragma unroll
    for (int s = 0; s < 2; s++) {
      bf16x8 bv;
#pragma unroll
      for (int t2 = 0; t2 < 8; t2++)
        bv[t2] = (bf16)Braw[(8 * q2[s] + t2) * 128 + n2[s]];
      *(bf16x8*)dstB2[s] = bv;
    }
    __syncthreads();  // Bs_f visible
    bf16x8 af[4], bfr[4];
#pragma unroll
    for (int i = 0; i < 4; i++)
      af[i] = *(const bf16x8*)(As_f + (wm4 + i) * 512 + lane * 8);
#pragma unroll
    for (int j = 0; j < 4; j++)
      bfr[j] = *(const bf16x8*)(Bs_f + (wn4 + j) * 512 + lane * 8);
#pragma unroll
    for (int i = 0; i < 4; i++)
#pragma unroll
      for (int j = 0; j < 4; j++)
        acc[i][j] = __builtin_amdgcn_mfma_f32_16x16x32_bf16(af[i], bfr[j],
                                                            acc[i][j], 0, 0, 0);
  }

  int base_r = mtile * 128, wm = (w & 1) * 64, wn = (w >> 1) * 64;
#pragma unroll
  for (int i = 0; i < 4; i++)
#pragma unroll
    for (int reg = 0; reg < 4; reg++) {
      int rg = base_r + wm + 16 * i + q * 4 + reg;
      if (rg < cnt) {
        int ent = ereg[rg];
        int tok = ent >> 1, slot = ent & 1;
        float wgt = tk_w[2 * tok + slot];
        float* orow = out + (size_t)tok * H_DIM + n0 + wn;
#pragma unroll
        for (int j = 0; j < 4; j++)
          atomicAdd(orow + 16 * j + r, wgt * acc[i][j][reg]);
      }
    }
}

extern "C" void kernel_launch(void* const* d_in, const int* in_sizes, int n_in,
                              void* d_out, int out_size, void* d_ws, size_t ws_size,
                              hipStream_t stream) {
  const float* x  = (const float*)d_in[0];
  const float* Wg = (const float*)d_in[1];
  const float* bg = (const float*)d_in[2];
  const float* We = (const float*)d_in[3];
  const float* be = (const float*)d_in[4];
  float* out = (float*)d_out;

  char* ws = (char*)d_ws;
  int*   counts  = (int*)(ws + WS_COUNTS);
  int*   entries = (int*)(ws + WS_ENTRIES);
  int*   tk_idx  = (int*)(ws + WS_TKIDX);
  float* tk_w    = (float*)(ws + WS_TKW);
  bf16*  xbf     = (bf16*)(ws + WS_XBF);
  bf16*  WeT     = (bf16*)(ws + WS_WET);

  bool big = (ws_size >= WS_BIG_NEED);

  hipLaunchKernelGGL(zero_counts, dim3(1), dim3(64), 0, stream, counts);
  hipLaunchKernelGGL(gating_kernel, dim3(B_TOK / 4), dim3(256), 0, stream,
                     x, Wg, bg, counts, entries, tk_idx, tk_w);
  hipLaunchKernelGGL(prefill_kernel, dim3(B_TOK * H_DIM / 4 / 256), dim3(256), 0,
                     stream, be, tk_idx, tk_w, out);
  if (big) {
    hipLaunchKernelGGL(xcvt_kernel, dim3(B_TOK * D_DIM / 8 / 256), dim3(256), 0,
                       stream, x, xbf);
    hipLaunchKernelGGL(transpose_cvt_we, dim3(H_DIM / 64, D_DIM / 64, E_NUM),
                       dim3(256), 0, stream, We, WeT);
    hipLaunchKernelGGL(moe_gemm_fast, dim3(H_DIM / 128, E_NUM * 32), dim3(256), 0,
                       stream, xbf, WeT, counts, entries, tk_w, out);
  } else {
    hipLaunchKernelGGL(moe_gemm_slow, dim3(H_DIM / 128, E_NUM * 32), dim3(256), 0,
                       stream, x, We, counts, entries, tk_w, out);
  }
}